// Round 4
// baseline (42.121 us; speedup 1.0000x reference)
//
#include <hip/hip_runtime.h>
#include <math.h>

#define NR 256   // rules
#define NF 128   // features
#define TB 16    // batch rows per main-kernel block

// ---------------------------------------------------------------------------
// prep: per (rule, feature) expand -(d-mu)^2/(2 s^2) = a*d^2 + b*d + c
//   a = -1/(2 s^2), b = 2 mu/(2 s^2), Cr[r] = sum_f -mu^2/(2 s^2)
// Writes TRANSPOSED (feature-major) so the main kernel's param reads are
// coalesced across lanes (lane = rule):
//   PT2[f][r] = {a, b}   (float2)
//   WT [f][r] = w3[r][1+f]
// ---------------------------------------------------------------------------
__global__ __launch_bounds__(128) void prep_kernel(
    const float* __restrict__ mu, const float* __restrict__ sigma,
    const float* __restrict__ w3,
    float2* __restrict__ PT2, float* __restrict__ WT,
    float* __restrict__ Cr, float* __restrict__ W0)
{
    const int r = blockIdx.x;
    const int f = threadIdx.x;
    const size_t i = (size_t)r * NF + f;
    const float s = sigma[i];
    const float m = mu[i];
    const float c = 0.5f / fmaxf(s * s, 1e-30f);  // clamp: avoid inf -> NaN
    const float a = -c;
    const float b = 2.0f * c * m;

    PT2[(size_t)f * NR + r] = make_float2(a, b);
    WT [(size_t)f * NR + r] = w3[(size_t)r * (NF + 1) + 1 + f];

    float cc = -c * m * m;
    #pragma unroll
    for (int off = 32; off > 0; off >>= 1) cc += __shfl_down(cc, off);
    __shared__ float tmp[2];
    if ((f & 63) == 0) tmp[f >> 6] = cc;
    __syncthreads();
    if (f == 0) {
        Cr[r] = tmp[0] + tmp[1];
        W0[r] = w3[(size_t)r * (NF + 1)];
    }
}

// ---------------------------------------------------------------------------
// main: thread = rule (256 threads), TB batch rows per block.
// Data rows are read at WAVE-UNIFORM addresses directly from global ->
// compiler emits s_load into SGPRs (SMEM pipe): no LDS tile, no syncthreads,
// no VALU/LDS cost for the broadcast operand.
//   S[b] = Cr + sum_f (a*d + b)*d ;  conq = W0 + sum_f d*W
//   rule = exp(S) - 28 ; out = sigmoid(sum_r rule*conq / sum_r rule)
// ---------------------------------------------------------------------------
__global__ __launch_bounds__(256) void fnn_main(
    const float* __restrict__ data,
    const float2* __restrict__ PT2, const float* __restrict__ WT,
    const float* __restrict__ Cr, const float* __restrict__ W0,
    float* __restrict__ out)
{
    __shared__ float red[TB][2][4];

    const int tid = threadIdx.x;                      // == rule id
    const int b0  = blockIdx.x * TB;
    const float* __restrict__ drow = data + (size_t)b0 * NF;  // uniform base

    float S[TB], Q[TB];
    #pragma unroll
    for (int b = 0; b < TB; ++b) { S[b] = 0.f; Q[b] = 0.f; }

    #pragma unroll 2
    for (int f = 0; f < NF; f += 4) {
        // lane-coalesced param loads (lane r -> consecutive addresses)
        const float2 ab0 = PT2[(size_t)(f + 0) * NR + tid];
        const float2 ab1 = PT2[(size_t)(f + 1) * NR + tid];
        const float2 ab2 = PT2[(size_t)(f + 2) * NR + tid];
        const float2 ab3 = PT2[(size_t)(f + 3) * NR + tid];
        const float w0  = WT[(size_t)(f + 0) * NR + tid];
        const float w1  = WT[(size_t)(f + 1) * NR + tid];
        const float w2  = WT[(size_t)(f + 2) * NR + tid];
        const float w3v = WT[(size_t)(f + 3) * NR + tid];

        #pragma unroll
        for (int b = 0; b < TB; ++b) {
            // wave-uniform address: scalarizes to s_load (SGPR broadcast)
            const float4 d4 = *(const float4*)(drow + (size_t)b * NF + f);
            float t;
            t = fmaf(ab0.x, d4.x, ab0.y); S[b] = fmaf(d4.x, t, S[b]); Q[b] = fmaf(d4.x, w0,  Q[b]);
            t = fmaf(ab1.x, d4.y, ab1.y); S[b] = fmaf(d4.y, t, S[b]); Q[b] = fmaf(d4.y, w1,  Q[b]);
            t = fmaf(ab2.x, d4.z, ab2.y); S[b] = fmaf(d4.z, t, S[b]); Q[b] = fmaf(d4.z, w2,  Q[b]);
            t = fmaf(ab3.x, d4.w, ab3.y); S[b] = fmaf(d4.w, t, S[b]); Q[b] = fmaf(d4.w, w3v, Q[b]);
        }
    }

    const float base = Cr[tid];
    const float bias = W0[tid];

    #pragma unroll
    for (int b = 0; b < TB; ++b) {
        float rule = __expf(S[b] + base) - 28.0f;   // RULE_OFFSET (10 ^ -18 == -28)
        float rc   = rule * (bias + Q[b]);
        #pragma unroll
        for (int off = 32; off > 0; off >>= 1) {
            rule += __shfl_down(rule, off);
            rc   += __shfl_down(rc,   off);
        }
        if ((tid & 63) == 0) {
            red[b][0][tid >> 6] = rule;
            red[b][1][tid >> 6] = rc;
        }
    }
    __syncthreads();

    if (tid < TB) {
        const float den = red[tid][0][0] + red[tid][0][1] + red[tid][0][2] + red[tid][0][3];
        const float num = red[tid][1][0] + red[tid][1][1] + red[tid][1][2] + red[tid][1][3];
        out[b0 + tid] = 1.0f / (1.0f + __expf(-(num / den)));
    }
}

// ---------------------------------------------------------------------------
// fallback (ws too small): fused version (round-2 structure, TB=8).
// ---------------------------------------------------------------------------
#define TBF 8
__global__ __launch_bounds__(256) void fnn_fused(
    const float* __restrict__ data,
    const float* __restrict__ mu, const float* __restrict__ sigma,
    const float* __restrict__ w3,
    float* __restrict__ out)
{
    __shared__ float d_tile[TBF][NF];
    __shared__ float red[TBF][2][4];

    const int tid = threadIdx.x;
    const int b0  = blockIdx.x * TBF;
    {
        const float4* src = (const float4*)(data + (size_t)b0 * NF);
        ((float4*)(&d_tile[0][0]))[tid] = src[tid];
    }
    __syncthreads();

    const float* mu_r = mu    + (size_t)tid * NF;
    const float* sg_r = sigma + (size_t)tid * NF;
    const float* w_r  = w3    + (size_t)tid * (NF + 1);

    float S[TBF], Q[TBF];
    #pragma unroll
    for (int b = 0; b < TBF; ++b) { S[b] = 0.f; Q[b] = 0.f; }

    #pragma unroll 2
    for (int f = 0; f < NF; f += 4) {
        const float4 m4 = *(const float4*)(mu_r + f);
        const float4 s4 = *(const float4*)(sg_r + f);
        const float w0 = w_r[1 + f + 0], w1 = w_r[1 + f + 1];
        const float w2 = w_r[1 + f + 2], w3v = w_r[1 + f + 3];
        float4 c4;
        c4.x = -0.5f / fmaxf(s4.x * s4.x, 1e-30f);
        c4.y = -0.5f / fmaxf(s4.y * s4.y, 1e-30f);
        c4.z = -0.5f / fmaxf(s4.z * s4.z, 1e-30f);
        c4.w = -0.5f / fmaxf(s4.w * s4.w, 1e-30f);
        #pragma unroll
        for (int b = 0; b < TBF; ++b) {
            const float4 d4 = *(const float4*)(&d_tile[b][f]);
            float t;
            t = d4.x - m4.x; S[b] = fmaf(t * t, c4.x, S[b]); Q[b] = fmaf(d4.x, w0,  Q[b]);
            t = d4.y - m4.y; S[b] = fmaf(t * t, c4.y, S[b]); Q[b] = fmaf(d4.y, w1,  Q[b]);
            t = d4.z - m4.z; S[b] = fmaf(t * t, c4.z, S[b]); Q[b] = fmaf(d4.z, w2,  Q[b]);
            t = d4.w - m4.w; S[b] = fmaf(t * t, c4.w, S[b]); Q[b] = fmaf(d4.w, w3v, Q[b]);
        }
    }

    const float bias = w_r[0];
    #pragma unroll
    for (int b = 0; b < TBF; ++b) {
        float rule = __expf(S[b]) - 28.0f;
        float rc   = rule * (bias + Q[b]);
        #pragma unroll
        for (int off = 32; off > 0; off >>= 1) {
            rule += __shfl_down(rule, off);
            rc   += __shfl_down(rc,   off);
        }
        if ((tid & 63) == 0) {
            red[b][0][tid >> 6] = rule;
            red[b][1][tid >> 6] = rc;
        }
    }
    __syncthreads();
    if (tid < TBF) {
        const float den = red[tid][0][0] + red[tid][0][1] + red[tid][0][2] + red[tid][0][3];
        const float num = red[tid][1][0] + red[tid][1][1] + red[tid][1][2] + red[tid][1][3];
        out[b0 + tid] = 1.0f / (1.0f + __expf(-(num / den)));
    }
}

extern "C" void kernel_launch(void* const* d_in, const int* in_sizes, int n_in,
                              void* d_out, int out_size, void* d_ws, size_t ws_size,
                              hipStream_t stream) {
    const float* data  = (const float*)d_in[0];
    const float* mu    = (const float*)d_in[1];
    const float* sigma = (const float*)d_in[2];
    const float* w3    = (const float*)d_in[3];
    float* out = (float*)d_out;

    const int batch = in_sizes[0] / NF;   // 8192
    // PT2 (2*NR*NF) + WT (NR*NF) + Cr (NR) + W0 (NR) floats == 395,264 B
    const size_t need = (size_t)(3 * NR * NF + 2 * NR) * sizeof(float);

    if (ws_size >= need) {
        float2* PT2 = (float2*)d_ws;
        float*  WT  = (float*)(PT2 + (size_t)NR * NF);
        float*  Cr  = WT + (size_t)NR * NF;
        float*  W0  = Cr + NR;
        prep_kernel<<<NR, NF, 0, stream>>>(mu, sigma, w3, PT2, WT, Cr, W0);
        fnn_main<<<batch / TB, 256, 0, stream>>>(data, PT2, WT, Cr, W0, out);
    } else {
        fnn_fused<<<batch / TBF, 256, 0, stream>>>(data, mu, sigma, w3, out);
    }
}

// Round 6
// 34.867 us; speedup vs baseline: 1.2081x; 1.2081x over previous
//
#include <hip/hip_runtime.h>
#include <math.h>

#define NR 256   // rules
#define NF 128   // features
#define BCOLS 32 // batch columns per block (MFMA N per wave-tile)

typedef short  s16x8  __attribute__((ext_vector_type(8)));   // 8 bf16 bit patterns
typedef __bf16 bf16x8 __attribute__((ext_vector_type(8)));
typedef float  f32x16 __attribute__((ext_vector_type(16)));  // MFMA 32x32 acc

__device__ __forceinline__ unsigned short f2bf(float x) {
    unsigned int u = __float_as_uint(x);
    unsigned int r = (u + 0x7FFFu + ((u >> 16) & 1u)) >> 16;  // RNE
    return (unsigned short)r;
}
__device__ __forceinline__ float bf2f(unsigned short b) {
    return __uint_as_float(((unsigned int)b) << 16);
}
__device__ __forceinline__ bf16x8 as_bf(s16x8 v) {
    return __builtin_bit_cast(bf16x8, v);
}
__device__ __forceinline__ f32x16 mfma_bf16(s16x8 a, s16x8 b, f32x16 acc) {
    // builtin: compiler handles MFMA hazards/nops (inline asm did NOT -> r5 NaN)
    return __builtin_amdgcn_mfma_f32_32x32x16_bf16(as_bf(a), as_bf(b), acc, 0, 0, 0);
}

// ---------------------------------------------------------------------------
// prep: expand -(d-mu)^2/(2 s^2) = u2*d^2 + u1*d + c,  u2=-1/(2s^2), u1=-2*u2*mu
// Params written hi/lo-split in MFMA A-fragment-major order:
//   frag id = rt*16 + ks  (rt = rule tile 0..7, ks = K16 step 0..15)
//   element: rule = rt*32 + (lane&31), k16 = (lane>>5)*8 + j
//   kk = ks*16 + k16: kk<128 -> u2[kk] (pairs d^2), kk>=128 -> u1[kk-128] (pairs d)
//   WC: kk<128 -> w_hi, kk>=128 -> w_lo
// Cr[r] = sum_f u2*mu^2 ; W0[r] = w3[r][0]
// ---------------------------------------------------------------------------
__global__ __launch_bounds__(128) void prep_kernel(
    const float* __restrict__ mu, const float* __restrict__ sigma,
    const float* __restrict__ w3,
    unsigned short* __restrict__ PH, unsigned short* __restrict__ PL,
    unsigned short* __restrict__ WC,
    float* __restrict__ Cr, float* __restrict__ W0)
{
    const int r = blockIdx.x;
    const int f = threadIdx.x;
    const size_t i = (size_t)r * NF + f;
    const float s  = sigma[i];
    const float m  = mu[i];
    const float u2 = -0.5f / fmaxf(s * s, 1e-30f);
    const float u1 = -2.0f * u2 * m;
    const float w  = w3[(size_t)r * (NF + 1) + 1 + f];

    const unsigned short ah = f2bf(u2); const unsigned short al = f2bf(u2 - bf2f(ah));
    const unsigned short bh = f2bf(u1); const unsigned short bl = f2bf(u1 - bf2f(bh));
    const unsigned short wh = f2bf(w);  const unsigned short wl = f2bf(w  - bf2f(wh));

    const int rt   = r >> 5;
    const int rc   = r & 31;
    const int ks   = f >> 4;
    const int k16  = f & 15;
    const int lane = (k16 >> 3) * 32 + rc;
    const int j    = k16 & 7;
    const size_t idx1 = ((size_t)((rt * 16 + ks)     * 64) + lane) * 8 + j;  // kk = f
    const size_t idx2 = ((size_t)((rt * 16 + 8 + ks) * 64) + lane) * 8 + j;  // kk = 128+f
    PH[idx1] = ah;  PH[idx2] = bh;
    PL[idx1] = al;  PL[idx2] = bl;
    WC[idx1] = wh;  WC[idx2] = wl;

    float cc = u2 * m * m;
    #pragma unroll
    for (int off = 32; off > 0; off >>= 1) cc += __shfl_down(cc, off);
    __shared__ float tmp[2];
    if ((f & 63) == 0) tmp[f >> 6] = cc;
    __syncthreads();
    if (f == 0) {
        Cr[r] = tmp[0] + tmp[1];
        W0[r] = w3[(size_t)r * (NF + 1)];
    }
}

// ---------------------------------------------------------------------------
// main: 512 threads = 8 waves; wave w owns rule tile w (32 rules); block owns
// 32 batch columns.  Swapped GEMM D[rule][batch]:
//   S = PH.[d2h;dh] + PL.[d2h;dh] + PH.[d2l;dl]   (3 passes; lo-passes kill
//       the |u2|~5e8 * 2^-9 rounding terms that could flip S past 0)
//   Q = [wh|wl].[dh;dh] + wh.dl
// Epilogue: rule = exp(min(S+Cr,0)) - 28 (true S<=0 -> clamp exact, bounds any
// residual corruption); per-lane reduce 16 regs; shfl_xor 32; LDS cross-wave.
// C/D layout (HW-verified m74/m101): col=lane&31, row=(reg&3)+8*(reg>>2)+4*(lane>>5)
// ---------------------------------------------------------------------------
__global__ __launch_bounds__(512) void fnn_mfma(
    const float* __restrict__ data,
    const unsigned short* __restrict__ PH, const unsigned short* __restrict__ PL,
    const unsigned short* __restrict__ WC,
    const float* __restrict__ Cr, const float* __restrict__ W0,
    float* __restrict__ out)
{
    __shared__ float sCr[NR], sW0[NR];
    __shared__ float redD[8][BCOLS], redN[8][BCOLS];

    const int tid = threadIdx.x;
    if (tid < NR) sCr[tid] = Cr[tid];
    else          sW0[tid - NR] = W0[tid - NR];

    const int wv   = tid >> 6;     // wave id == rule tile
    const int lane = tid & 63;
    const int col  = lane & 31;
    const int half = lane >> 5;
    const int b0   = blockIdx.x * BCOLS;

    // ---- build data fragments: lane holds its column's 8 consecutive feats/step
    s16x8 Xd2[8], Xd[8], Xdl[8], Xd2l[8];
    const float* row = data + (size_t)(b0 + col) * NF;
    #pragma unroll
    for (int ks = 0; ks < 8; ++ks) {
        const float4 v0 = *(const float4*)(row + ks * 16 + half * 8);
        const float4 v1 = *(const float4*)(row + ks * 16 + half * 8 + 4);
        const float dv[8] = {v0.x, v0.y, v0.z, v0.w, v1.x, v1.y, v1.z, v1.w};
        #pragma unroll
        for (int j = 0; j < 8; ++j) {
            const float d  = dv[j];
            const float d2 = d * d;
            const unsigned short dh  = f2bf(d);
            const unsigned short d2h = f2bf(d2);
            Xd  [ks][j] = (short)dh;
            Xdl [ks][j] = (short)f2bf(d  - bf2f(dh));
            Xd2 [ks][j] = (short)d2h;
            Xd2l[ks][j] = (short)f2bf(d2 - bf2f(d2h));
        }
    }

    const s16x8* PHf = (const s16x8*)PH;
    const s16x8* PLf = (const s16x8*)PL;
    const s16x8* WCf = (const s16x8*)WC;
    const int fbase = wv * 16 * 64 + lane;   // entry = (wv*16+ks)*64 + lane

    f32x16 accS, accQ;
    #pragma unroll
    for (int e = 0; e < 16; ++e) { accS[e] = 0.f; accQ[e] = 0.f; }

    // S pass 1: params-hi . [d2h ; dh]
    #pragma unroll
    for (int ks = 0; ks < 16; ++ks) {
        const s16x8 a = PHf[fbase + ks * 64];
        const s16x8 b = (ks < 8) ? Xd2[ks & 7] : Xd[ks & 7];
        accS = mfma_bf16(a, b, accS);
    }
    // S pass 2: params-lo . [d2h ; dh]
    #pragma unroll
    for (int ks = 0; ks < 16; ++ks) {
        const s16x8 a = PLf[fbase + ks * 64];
        const s16x8 b = (ks < 8) ? Xd2[ks & 7] : Xd[ks & 7];
        accS = mfma_bf16(a, b, accS);
    }
    // S pass 3: params-hi . [d2l ; dl]   (kills bf16(d^2)/bf16(d) rounding)
    #pragma unroll
    for (int ks = 0; ks < 16; ++ks) {
        const s16x8 a = PHf[fbase + ks * 64];
        const s16x8 b = (ks < 8) ? Xd2l[ks & 7] : Xdl[ks & 7];
        accS = mfma_bf16(a, b, accS);
    }
    // Q pass 1: [w_hi | w_lo] . [dh ; dh]
    #pragma unroll
    for (int ks = 0; ks < 16; ++ks) {
        accQ = mfma_bf16(WCf[fbase + ks * 64], Xd[ks & 7], accQ);
    }
    // Q pass 2: w_hi . dl
    #pragma unroll
    for (int ks = 0; ks < 8; ++ks) {
        accQ = mfma_bf16(WCf[fbase + ks * 64], Xdl[ks], accQ);
    }

    __syncthreads();   // sCr/sW0 visible

    float den_p = 0.f, num_p = 0.f;
    #pragma unroll
    for (int reg = 0; reg < 16; ++reg) {
        const int rloc = (reg & 3) + 8 * (reg >> 2) + 4 * half;
        const int rule = wv * 32 + rloc;
        const float S  = accS[reg] + sCr[rule];
        const float rv = __expf(fminf(S, 0.f)) - 28.0f;   // RULE_OFFSET (10 ^ -18 == -28)
        const float cq = accQ[reg] + sW0[rule];
        den_p += rv;
        num_p += rv * cq;
    }
    den_p += __shfl_xor(den_p, 32);
    num_p += __shfl_xor(num_p, 32);
    if (half == 0) { redD[wv][col] = den_p; redN[wv][col] = num_p; }
    __syncthreads();

    if (tid < BCOLS) {
        float den = 0.f, num = 0.f;
        #pragma unroll
        for (int w = 0; w < 8; ++w) { den += redD[w][tid]; num += redN[w][tid]; }
        out[b0 + tid] = 1.0f / (1.0f + __expf(-(num / den)));
    }
}

// ---------------------------------------------------------------------------
// fallback (ws too small): fused f32 version (round-2 structure, known-good).
// ---------------------------------------------------------------------------
#define TBF 8
__global__ __launch_bounds__(256) void fnn_fused(
    const float* __restrict__ data,
    const float* __restrict__ mu, const float* __restrict__ sigma,
    const float* __restrict__ w3,
    float* __restrict__ out)
{
    __shared__ float d_tile[TBF][NF];
    __shared__ float red[TBF][2][4];

    const int tid = threadIdx.x;
    const int b0  = blockIdx.x * TBF;
    {
        const float4* src = (const float4*)(data + (size_t)b0 * NF);
        ((float4*)(&d_tile[0][0]))[tid] = src[tid];
    }
    __syncthreads();

    const float* mu_r = mu    + (size_t)tid * NF;
    const float* sg_r = sigma + (size_t)tid * NF;
    const float* w_r  = w3    + (size_t)tid * (NF + 1);

    float S[TBF], Q[TBF];
    #pragma unroll
    for (int b = 0; b < TBF; ++b) { S[b] = 0.f; Q[b] = 0.f; }

    #pragma unroll 2
    for (int f = 0; f < NF; f += 4) {
        const float4 m4 = *(const float4*)(mu_r + f);
        const float4 s4 = *(const float4*)(sg_r + f);
        const float w0 = w_r[1 + f + 0], w1 = w_r[1 + f + 1];
        const float w2 = w_r[1 + f + 2], w3v = w_r[1 + f + 3];
        float4 c4;
        c4.x = -0.5f / fmaxf(s4.x * s4.x, 1e-30f);
        c4.y = -0.5f / fmaxf(s4.y * s4.y, 1e-30f);
        c4.z = -0.5f / fmaxf(s4.z * s4.z, 1e-30f);
        c4.w = -0.5f / fmaxf(s4.w * s4.w, 1e-30f);
        #pragma unroll
        for (int b = 0; b < TBF; ++b) {
            const float4 d4 = *(const float4*)(&d_tile[b][f]);
            float t;
            t = d4.x - m4.x; S[b] = fmaf(t * t, c4.x, S[b]); Q[b] = fmaf(d4.x, w0,  Q[b]);
            t = d4.y - m4.y; S[b] = fmaf(t * t, c4.y, S[b]); Q[b] = fmaf(d4.y, w1,  Q[b]);
            t = d4.z - m4.z; S[b] = fmaf(t * t, c4.z, S[b]); Q[b] = fmaf(d4.z, w2,  Q[b]);
            t = d4.w - m4.w; S[b] = fmaf(t * t, c4.w, S[b]); Q[b] = fmaf(d4.w, w3v, Q[b]);
        }
    }

    const float bias = w_r[0];
    #pragma unroll
    for (int b = 0; b < TBF; ++b) {
        float rule = __expf(S[b]) - 28.0f;
        float rc   = rule * (bias + Q[b]);
        #pragma unroll
        for (int off = 32; off > 0; off >>= 1) {
            rule += __shfl_down(rule, off);
            rc   += __shfl_down(rc,   off);
        }
        if ((tid & 63) == 0) {
            red[b][0][tid >> 6] = rule;
            red[b][1][tid >> 6] = rc;
        }
    }
    __syncthreads();
    if (tid < TBF) {
        const float den = red[tid][0][0] + red[tid][0][1] + red[tid][0][2] + red[tid][0][3];
        const float num = red[tid][1][0] + red[tid][1][1] + red[tid][1][2] + red[tid][1][3];
        out[b0 + tid] = 1.0f / (1.0f + __expf(-(num / den)));
    }
}

extern "C" void kernel_launch(void* const* d_in, const int* in_sizes, int n_in,
                              void* d_out, int out_size, void* d_ws, size_t ws_size,
                              hipStream_t stream) {
    const float* data  = (const float*)d_in[0];
    const float* mu    = (const float*)d_in[1];
    const float* sigma = (const float*)d_in[2];
    const float* w3    = (const float*)d_in[3];
    float* out = (float*)d_out;

    const int batch = in_sizes[0] / NF;   // 8192
    // PH + PL + WC (3 x 64K bf16 = 3 x 128 KiB) + Cr + W0 = 395,264 B
    const size_t need = 3u * 65536u * sizeof(unsigned short) + 2u * NR * sizeof(float);

    if (ws_size >= need && (batch % BCOLS) == 0) {
        unsigned short* PH = (unsigned short*)d_ws;
        unsigned short* PL = PH + 65536;
        unsigned short* WC = PL + 65536;
        float* Cr = (float*)(WC + 65536);
        float* W0 = Cr + NR;
        prep_kernel<<<NR, NF, 0, stream>>>(mu, sigma, w3, PH, PL, WC, Cr, W0);
        fnn_mfma<<<batch / BCOLS, 512, 0, stream>>>(data, PH, PL, WC, Cr, W0, out);
    } else {
        fnn_fused<<<batch / TBF, 256, 0, stream>>>(data, mu, sigma, w3, out);
    }
}

// Round 7
// 20.912 us; speedup vs baseline: 2.0143x; 1.6673x over previous
//
#include <hip/hip_runtime.h>
#include <math.h>

#define NR 256   // rules
#define NF 128   // features
#define BCOLS 32 // batch columns per block (MFMA N)

typedef short  s16x8  __attribute__((ext_vector_type(8)));   // 8 bf16 bit patterns
typedef __bf16 bf16x8 __attribute__((ext_vector_type(8)));
typedef float  f32x16 __attribute__((ext_vector_type(16)));  // MFMA 32x32 acc

__device__ __forceinline__ unsigned short f2bf(float x) {
    unsigned int u = __float_as_uint(x);
    unsigned int r = (u + 0x7FFFu + ((u >> 16) & 1u)) >> 16;  // RNE
    return (unsigned short)r;
}
__device__ __forceinline__ float bf2f(unsigned short b) {
    return __uint_as_float(((unsigned int)b) << 16);
}
__device__ __forceinline__ bf16x8 as_bf(s16x8 v) {
    return __builtin_bit_cast(bf16x8, v);
}
__device__ __forceinline__ f32x16 mfma_bf16(s16x8 a, s16x8 b, f32x16 acc) {
    return __builtin_amdgcn_mfma_f32_32x32x16_bf16(as_bf(a), as_bf(b), acc, 0, 0, 0);
}

// ---------------------------------------------------------------------------
// prep: expand -(d-mu)^2/(2 s^2) = u2*d^2 + u1*d + c,  u2=-1/(2s^2), u1=-2*u2*mu
// Params hi/lo-split, MFMA A-fragment-major (validated r6):
//   frag id = rt*16 + ks ; element: rule = rt*32+(lane&31), k16=(lane>>5)*8+j
//   kk = ks*16+k16: kk<128 -> u2[kk] (pairs d^2), kk>=128 -> u1[kk-128] (pairs d)
//   WC: kk<128 -> w_hi, kk>=128 -> w_lo
// ---------------------------------------------------------------------------
__global__ __launch_bounds__(128) void prep_kernel(
    const float* __restrict__ mu, const float* __restrict__ sigma,
    const float* __restrict__ w3,
    unsigned short* __restrict__ PH, unsigned short* __restrict__ PL,
    unsigned short* __restrict__ WC,
    float* __restrict__ Cr, float* __restrict__ W0)
{
    const int r = blockIdx.x;
    const int f = threadIdx.x;
    const size_t i = (size_t)r * NF + f;
    const float s  = sigma[i];
    const float m  = mu[i];
    const float u2 = -0.5f / fmaxf(s * s, 1e-30f);
    const float u1 = -2.0f * u2 * m;
    const float w  = w3[(size_t)r * (NF + 1) + 1 + f];

    const unsigned short ah = f2bf(u2); const unsigned short al = f2bf(u2 - bf2f(ah));
    const unsigned short bh = f2bf(u1); const unsigned short bl = f2bf(u1 - bf2f(bh));
    const unsigned short wh = f2bf(w);  const unsigned short wl = f2bf(w  - bf2f(wh));

    const int rt   = r >> 5;
    const int rc   = r & 31;
    const int ks   = f >> 4;
    const int k16  = f & 15;
    const int lane = (k16 >> 3) * 32 + rc;
    const int j    = k16 & 7;
    const size_t idx1 = ((size_t)((rt * 16 + ks)     * 64) + lane) * 8 + j;  // kk = f
    const size_t idx2 = ((size_t)((rt * 16 + 8 + ks) * 64) + lane) * 8 + j;  // kk = 128+f
    PH[idx1] = ah;  PH[idx2] = bh;
    PL[idx1] = al;  PL[idx2] = bl;
    WC[idx1] = wh;  WC[idx2] = wl;

    float cc = u2 * m * m;
    #pragma unroll
    for (int off = 32; off > 0; off >>= 1) cc += __shfl_down(cc, off);
    __shared__ float tmp[2];
    if ((f & 63) == 0) tmp[f >> 6] = cc;
    __syncthreads();
    if (f == 0) {
        Cr[r] = tmp[0] + tmp[1];
        W0[r] = w3[(size_t)r * (NF + 1)];
    }
}

// ---------------------------------------------------------------------------
// main: 512 threads = 8 waves; wave = rule tile (32 rules); block = 32 batch
// cols. B-fragments (data-derived, identical for all waves!) are built ONCE
// cooperatively into LDS (r6 built them per-wave in registers: 128 VGPR +
// 8x redundant VALU). Single fused K-loop: per ks reuse A-frags (PH used by
// 2 MFMAs), 1-deep register prefetch of next-ks A-frags.
//   S = PH.[d2h;dh] + PL.[d2h;dh] + PH.[d2l;dl]
//   Q = [wh|wl].[dh;dh] + wh.dl
// Epilogue: rule=exp(min(S+Cr,0))-28; 16-reg reduce; shfl_xor 32; LDS combine.
// C/D layout (HW-verified): col=lane&31, row=(reg&3)+8*(reg>>2)+4*(lane>>5)
// ---------------------------------------------------------------------------
__global__ __launch_bounds__(512) void fnn_mfma(
    const float* __restrict__ data,
    const unsigned short* __restrict__ PH, const unsigned short* __restrict__ PL,
    const unsigned short* __restrict__ WC,
    const float* __restrict__ Cr, const float* __restrict__ W0,
    float* __restrict__ out)
{
    __shared__ s16x8 sXd2[8][64], sXd[8][64], sXd2l[8][64], sXdl[8][64]; // 32 KB
    __shared__ float sCr[NR], sW0[NR];
    __shared__ float redD[8][BCOLS], redN[8][BCOLS];

    const int tid = threadIdx.x;
    if (tid < NR) sCr[tid] = Cr[tid];
    else          sW0[tid - NR] = W0[tid - NR];

    const int b0 = blockIdx.x * BCOLS;

    // ---- cooperative B-frag build: thread (bks, bln) builds 4 LDS entries
    {
        const int bks = tid >> 6;        // 0..7 : K16 step within a K-half
        const int bln = tid & 63;        // destination lane id
        const float* p = data + (size_t)(b0 + (bln & 31)) * NF
                              + bks * 16 + (bln >> 5) * 8;
        const float4 v0 = *(const float4*)(p);
        const float4 v1 = *(const float4*)(p + 4);
        const float dv[8] = {v0.x, v0.y, v0.z, v0.w, v1.x, v1.y, v1.z, v1.w};
        s16x8 e_d, e_dl, e_d2, e_d2l;
        #pragma unroll
        for (int j = 0; j < 8; ++j) {
            const float d  = dv[j];
            const float d2 = d * d;
            const unsigned short dh  = f2bf(d);
            const unsigned short d2h = f2bf(d2);
            e_d  [j] = (short)dh;
            e_dl [j] = (short)f2bf(d  - bf2f(dh));
            e_d2 [j] = (short)d2h;
            e_d2l[j] = (short)f2bf(d2 - bf2f(d2h));
        }
        sXd  [bks][bln] = e_d;
        sXdl [bks][bln] = e_dl;
        sXd2 [bks][bln] = e_d2;
        sXd2l[bks][bln] = e_d2l;
    }
    __syncthreads();

    const int wv   = tid >> 6;     // wave id == rule tile
    const int lane = tid & 63;
    const int col  = lane & 31;
    const int half = lane >> 5;

    const s16x8* PHp = (const s16x8*)PH + (size_t)wv * 16 * 64 + lane;
    const s16x8* PLp = (const s16x8*)PL + (size_t)wv * 16 * 64 + lane;
    const s16x8* WCp = (const s16x8*)WC + (size_t)wv * 16 * 64 + lane;

    f32x16 accS, accQ;
    #pragma unroll
    for (int e = 0; e < 16; ++e) { accS[e] = 0.f; accQ[e] = 0.f; }

    s16x8 a0 = PHp[0], a1 = PLp[0], a2 = WCp[0];
    #pragma unroll
    for (int ks = 0; ks < 16; ++ks) {
        s16x8 n0, n1, n2;
        if (ks < 15) {                      // prefetch next-ks A-frags
            n0 = PHp[(ks + 1) * 64];
            n1 = PLp[(ks + 1) * 64];
            n2 = WCp[(ks + 1) * 64];
        }
        const int km = ks & 7;
        const s16x8 bh = (ks < 8) ? sXd2[km][lane]  : sXd[km][lane];
        const s16x8 bl = (ks < 8) ? sXd2l[km][lane] : sXdl[km][lane];
        accS = mfma_bf16(a0, bh, accS);     // params-hi . [d2h ; dh]
        accS = mfma_bf16(a1, bh, accS);     // params-lo . [d2h ; dh]
        accS = mfma_bf16(a0, bl, accS);     // params-hi . [d2l ; dl]
        if (ks < 8) {
            accQ = mfma_bf16(a2, sXd[km][lane],  accQ);   // w_hi . dh
            accQ = mfma_bf16(a2, sXdl[km][lane], accQ);   // w_hi . dl
        } else {
            accQ = mfma_bf16(a2, bh, accQ);               // w_lo . dh
        }
        a0 = n0; a1 = n1; a2 = n2;
    }

    float den_p = 0.f, num_p = 0.f;
    #pragma unroll
    for (int reg = 0; reg < 16; ++reg) {
        const int rloc = (reg & 3) + 8 * (reg >> 2) + 4 * half;
        const int rule = wv * 32 + rloc;
        const float S  = accS[reg] + sCr[rule];
        const float rv = __expf(fminf(S, 0.f)) - 28.0f;   // RULE_OFFSET (10 ^ -18 == -28)
        const float cq = accQ[reg] + sW0[rule];
        den_p += rv;
        num_p += rv * cq;
    }
    den_p += __shfl_xor(den_p, 32);
    num_p += __shfl_xor(num_p, 32);
    if (half == 0) { redD[wv][col] = den_p; redN[wv][col] = num_p; }
    __syncthreads();

    if (tid < BCOLS) {
        float den = 0.f, num = 0.f;
        #pragma unroll
        for (int w = 0; w < 8; ++w) { den += redD[w][tid]; num += redN[w][tid]; }
        out[b0 + tid] = 1.0f / (1.0f + __expf(-(num / den)));
    }
}

// ---------------------------------------------------------------------------
// fallback (ws too small): fused f32 version (round-2 structure, known-good).
// ---------------------------------------------------------------------------
#define TBF 8
__global__ __launch_bounds__(256) void fnn_fused(
    const float* __restrict__ data,
    const float* __restrict__ mu, const float* __restrict__ sigma,
    const float* __restrict__ w3,
    float* __restrict__ out)
{
    __shared__ float d_tile[TBF][NF];
    __shared__ float red[TBF][2][4];

    const int tid = threadIdx.x;
    const int b0  = blockIdx.x * TBF;
    {
        const float4* src = (const float4*)(data + (size_t)b0 * NF);
        ((float4*)(&d_tile[0][0]))[tid] = src[tid];
    }
    __syncthreads();

    const float* mu_r = mu    + (size_t)tid * NF;
    const float* sg_r = sigma + (size_t)tid * NF;
    const float* w_r  = w3    + (size_t)tid * (NF + 1);

    float S[TBF], Q[TBF];
    #pragma unroll
    for (int b = 0; b < TBF; ++b) { S[b] = 0.f; Q[b] = 0.f; }

    #pragma unroll 2
    for (int f = 0; f < NF; f += 4) {
        const float4 m4 = *(const float4*)(mu_r + f);
        const float4 s4 = *(const float4*)(sg_r + f);
        const float w0 = w_r[1 + f + 0], w1 = w_r[1 + f + 1];
        const float w2 = w_r[1 + f + 2], w3v = w_r[1 + f + 3];
        float4 c4;
        c4.x = -0.5f / fmaxf(s4.x * s4.x, 1e-30f);
        c4.y = -0.5f / fmaxf(s4.y * s4.y, 1e-30f);
        c4.z = -0.5f / fmaxf(s4.z * s4.z, 1e-30f);
        c4.w = -0.5f / fmaxf(s4.w * s4.w, 1e-30f);
        #pragma unroll
        for (int b = 0; b < TBF; ++b) {
            const float4 d4 = *(const float4*)(&d_tile[b][f]);
            float t;
            t = d4.x - m4.x; S[b] = fmaf(t * t, c4.x, S[b]); Q[b] = fmaf(d4.x, w0,  Q[b]);
            t = d4.y - m4.y; S[b] = fmaf(t * t, c4.y, S[b]); Q[b] = fmaf(d4.y, w1,  Q[b]);
            t = d4.z - m4.z; S[b] = fmaf(t * t, c4.z, S[b]); Q[b] = fmaf(d4.z, w2,  Q[b]);
            t = d4.w - m4.w; S[b] = fmaf(t * t, c4.w, S[b]); Q[b] = fmaf(d4.w, w3v, Q[b]);
        }
    }

    const float bias = w_r[0];
    #pragma unroll
    for (int b = 0; b < TBF; ++b) {
        float rule = __expf(S[b]) - 28.0f;
        float rc   = rule * (bias + Q[b]);
        #pragma unroll
        for (int off = 32; off > 0; off >>= 1) {
            rule += __shfl_down(rule, off);
            rc   += __shfl_down(rc,   off);
        }
        if ((tid & 63) == 0) {
            red[b][0][tid >> 6] = rule;
            red[b][1][tid >> 6] = rc;
        }
    }
    __syncthreads();
    if (tid < TBF) {
        const float den = red[tid][0][0] + red[tid][0][1] + red[tid][0][2] + red[tid][0][3];
        const float num = red[tid][1][0] + red[tid][1][1] + red[tid][1][2] + red[tid][1][3];
        out[b0 + tid] = 1.0f / (1.0f + __expf(-(num / den)));
    }
}

extern "C" void kernel_launch(void* const* d_in, const int* in_sizes, int n_in,
                              void* d_out, int out_size, void* d_ws, size_t ws_size,
                              hipStream_t stream) {
    const float* data  = (const float*)d_in[0];
    const float* mu    = (const float*)d_in[1];
    const float* sigma = (const float*)d_in[2];
    const float* w3    = (const float*)d_in[3];
    float* out = (float*)d_out;

    const int batch = in_sizes[0] / NF;   // 8192
    // PH + PL + WC (3 x 64K bf16 = 3 x 128 KiB) + Cr + W0 = 395,264 B
    const size_t need = 3u * 65536u * sizeof(unsigned short) + 2u * NR * sizeof(float);

    if (ws_size >= need && (batch % BCOLS) == 0) {
        unsigned short* PH = (unsigned short*)d_ws;
        unsigned short* PL = PH + 65536;
        unsigned short* WC = PL + 65536;
        float* Cr = (float*)(WC + 65536);
        float* W0 = Cr + NR;
        prep_kernel<<<NR, NF, 0, stream>>>(mu, sigma, w3, PH, PL, WC, Cr, W0);
        fnn_mfma<<<batch / BCOLS, 512, 0, stream>>>(data, PH, PL, WC, Cr, W0, out);
    } else {
        fnn_fused<<<batch / TBF, 256, 0, stream>>>(data, mu, sigma, w3, out);
    }
}

// Round 8
// 18.201 us; speedup vs baseline: 2.3142x; 1.1489x over previous
//
#include <hip/hip_runtime.h>
#include <math.h>

#define NR 256   // rules
#define NF 128   // features
#define BCOLS 32 // batch columns per block (MFMA N)

typedef short  s16x8  __attribute__((ext_vector_type(8)));   // 8 bf16 bit patterns
typedef __bf16 bf16x8 __attribute__((ext_vector_type(8)));
typedef float  f32x16 __attribute__((ext_vector_type(16)));  // MFMA 32x32 acc

__device__ __forceinline__ unsigned short f2bf(float x) {
    unsigned int u = __float_as_uint(x);
    unsigned int r = (u + 0x7FFFu + ((u >> 16) & 1u)) >> 16;  // RNE
    return (unsigned short)r;
}
__device__ __forceinline__ float bf2f(unsigned short b) {
    return __uint_as_float(((unsigned int)b) << 16);
}
__device__ __forceinline__ bf16x8 as_bf(s16x8 v) {
    return __builtin_bit_cast(bf16x8, v);
}
__device__ __forceinline__ f32x16 mfma_bf16(s16x8 a, s16x8 b, f32x16 acc) {
    return __builtin_amdgcn_mfma_f32_32x32x16_bf16(as_bf(a), as_bf(b), acc, 0, 0, 0);
}

// ---------------------------------------------------------------------------
// prep (unchanged, validated r6/r7): -(d-mu)^2/(2 s^2) = u2*d^2 + u1*d + c
//   frag id = rt*16 + ks ; element: rule = rt*32+(lane&31), k16=(lane>>5)*8+j
//   kk = ks*16+k16: kk<128 -> u2[kk] (pairs d^2), kk>=128 -> u1[kk-128] (pairs d)
//   WC: kk<128 -> w_hi, kk>=128 -> w_lo
// ---------------------------------------------------------------------------
__global__ __launch_bounds__(128) void prep_kernel(
    const float* __restrict__ mu, const float* __restrict__ sigma,
    const float* __restrict__ w3,
    unsigned short* __restrict__ PH, unsigned short* __restrict__ PL,
    unsigned short* __restrict__ WC,
    float* __restrict__ Cr, float* __restrict__ W0)
{
    const int r = blockIdx.x;
    const int f = threadIdx.x;
    const size_t i = (size_t)r * NF + f;
    const float s  = sigma[i];
    const float m  = mu[i];
    const float u2 = -0.5f / fmaxf(s * s, 1e-30f);
    const float u1 = -2.0f * u2 * m;
    const float w  = w3[(size_t)r * (NF + 1) + 1 + f];

    const unsigned short ah = f2bf(u2); const unsigned short al = f2bf(u2 - bf2f(ah));
    const unsigned short bh = f2bf(u1); const unsigned short bl = f2bf(u1 - bf2f(bh));
    const unsigned short wh = f2bf(w);  const unsigned short wl = f2bf(w  - bf2f(wh));

    const int rt   = r >> 5;
    const int rc   = r & 31;
    const int ks   = f >> 4;
    const int k16  = f & 15;
    const int lane = (k16 >> 3) * 32 + rc;
    const int j    = k16 & 7;
    const size_t idx1 = ((size_t)((rt * 16 + ks)     * 64) + lane) * 8 + j;  // kk = f
    const size_t idx2 = ((size_t)((rt * 16 + 8 + ks) * 64) + lane) * 8 + j;  // kk = 128+f
    PH[idx1] = ah;  PH[idx2] = bh;
    PL[idx1] = al;  PL[idx2] = bl;
    WC[idx1] = wh;  WC[idx2] = wl;

    float cc = u2 * m * m;
    #pragma unroll
    for (int off = 32; off > 0; off >>= 1) cc += __shfl_down(cc, off);
    __shared__ float tmp[2];
    if ((f & 63) == 0) tmp[f >> 6] = cc;
    __syncthreads();
    if (f == 0) {
        Cr[r] = tmp[0] + tmp[1];
        W0[r] = w3[(size_t)r * (NF + 1)];
    }
}

// ---------------------------------------------------------------------------
// main: 512 thr = 8 waves; wave = rule tile; block = 32 batch cols.
// B-fragments in TWO LDS arrays (selection = address math, no reg arrays):
//   sBH[ks][lane]: ks<8 -> bf16(d^2) ; ks>=8 -> bf16(d)     (features (ks&7)*16..)
//   sBL[ks][lane]: ks<8 -> lo(d^2)   ; ks>=8 -> lo(d)
// K-loop: #pragma unroll 1 + strict 1-deep prefetch -> max 6 loads in flight
// (bounded VGPR by construction; r7's full unroll could hoist 45 loads -> spill).
//   S = PH.bh (accS0)  +  PL.bh + PH.bl (accS1)
//   Q = ks<8: WC.sBH[ks+8] + WC.sBL[ks+8] ; ks>=8: WC.bh   (accQ)
// Epilogue: rule=exp(min(S+Cr,0))-28; per-lane 16-reg reduce; shfl_xor 32; LDS.
// C/D layout (HW-verified): col=lane&31, row=(reg&3)+8*(reg>>2)+4*(lane>>5)
// ---------------------------------------------------------------------------
__global__ __launch_bounds__(512) void fnn_mfma(
    const float* __restrict__ data,
    const unsigned short* __restrict__ PH, const unsigned short* __restrict__ PL,
    const unsigned short* __restrict__ WC,
    const float* __restrict__ Cr, const float* __restrict__ W0,
    float* __restrict__ out)
{
    __shared__ s16x8 sBH[16][64], sBL[16][64];   // 32 KB
    __shared__ float sCr[NR], sW0[NR];
    __shared__ float redD[8][BCOLS], redN[8][BCOLS];

    const int tid = threadIdx.x;
    if (tid < NR) sCr[tid] = Cr[tid];
    else          sW0[tid - NR] = W0[tid - NR];

    const int b0 = blockIdx.x * BCOLS;

    // ---- cooperative B build: thread (bks,bln) -> 4 LDS entries
    {
        const int bks = tid >> 6;        // 0..7
        const int bln = tid & 63;
        const float* p = data + (size_t)(b0 + (bln & 31)) * NF
                              + bks * 16 + (bln >> 5) * 8;
        const float4 v0 = *(const float4*)(p);
        const float4 v1 = *(const float4*)(p + 4);
        const float dv[8] = {v0.x, v0.y, v0.z, v0.w, v1.x, v1.y, v1.z, v1.w};
        s16x8 e_d, e_dl, e_d2, e_d2l;
        #pragma unroll
        for (int j = 0; j < 8; ++j) {
            const float d  = dv[j];
            const float d2 = d * d;
            const unsigned short dh  = f2bf(d);
            const unsigned short d2h = f2bf(d2);
            e_d  [j] = (short)dh;
            e_dl [j] = (short)f2bf(d  - bf2f(dh));
            e_d2 [j] = (short)d2h;
            e_d2l[j] = (short)f2bf(d2 - bf2f(d2h));
        }
        sBH[bks    ][bln] = e_d2;   // ks<8  : d^2 hi
        sBL[bks    ][bln] = e_d2l;  // ks<8  : d^2 lo
        sBH[bks + 8][bln] = e_d;    // ks>=8 : d hi
        sBL[bks + 8][bln] = e_dl;   // ks>=8 : d lo
    }
    __syncthreads();

    const int wv   = tid >> 6;     // wave id == rule tile
    const int lane = tid & 63;
    const int col  = lane & 31;
    const int half = lane >> 5;

    const s16x8* PHp = (const s16x8*)PH + (size_t)wv * 16 * 64 + lane;
    const s16x8* PLp = (const s16x8*)PL + (size_t)wv * 16 * 64 + lane;
    const s16x8* WCp = (const s16x8*)WC + (size_t)wv * 16 * 64 + lane;

    f32x16 accS0, accS1, accQ;
    #pragma unroll
    for (int e = 0; e < 16; ++e) { accS0[e] = 0.f; accS1[e] = 0.f; accQ[e] = 0.f; }

    s16x8 a0 = PHp[0], a1 = PLp[0], a2 = WCp[0];
    #pragma unroll 1
    for (int ks = 0; ks < 16; ++ks) {
        // strict 1-deep prefetch (clamped index keeps it branchless & bounded)
        const int nofs = ((ks < 15) ? (ks + 1) : ks) * 64;
        const s16x8 n0 = PHp[nofs];
        const s16x8 n1 = PLp[nofs];
        const s16x8 n2 = WCp[nofs];

        const s16x8 bh = sBH[ks][lane];
        const s16x8 bl = sBL[ks][lane];
        accS0 = mfma_bf16(a0, bh, accS0);   // PH . {d2h|dh}
        accS1 = mfma_bf16(a1, bh, accS1);   // PL . {d2h|dh}
        accS1 = mfma_bf16(a0, bl, accS1);   // PH . {d2l|dl}
        if (ks < 8) {                        // uniform branch
            accQ = mfma_bf16(a2, sBH[ks + 8][lane], accQ);  // w_hi . dh
            accQ = mfma_bf16(a2, sBL[ks + 8][lane], accQ);  // w_hi . dl
        } else {
            accQ = mfma_bf16(a2, bh, accQ);                 // w_lo . dh
        }
        a0 = n0; a1 = n1; a2 = n2;
    }

    float den_p = 0.f, num_p = 0.f;
    #pragma unroll
    for (int reg = 0; reg < 16; ++reg) {
        const int rloc = (reg & 3) + 8 * (reg >> 2) + 4 * half;
        const int rule = wv * 32 + rloc;
        const float S  = accS0[reg] + accS1[reg] + sCr[rule];
        const float rv = __expf(fminf(S, 0.f)) - 28.0f;   // RULE_OFFSET (10 ^ -18 == -28)
        const float cq = accQ[reg] + sW0[rule];
        den_p += rv;
        num_p += rv * cq;
    }
    den_p += __shfl_xor(den_p, 32);
    num_p += __shfl_xor(num_p, 32);
    if (half == 0) { redD[wv][col] = den_p; redN[wv][col] = num_p; }
    __syncthreads();

    if (tid < BCOLS) {
        float den = 0.f, num = 0.f;
        #pragma unroll
        for (int w = 0; w < 8; ++w) { den += redD[w][tid]; num += redN[w][tid]; }
        out[b0 + tid] = 1.0f / (1.0f + __expf(-(num / den)));
    }
}

// ---------------------------------------------------------------------------
// fallback (ws too small): fused f32 version (round-2 structure, known-good).
// ---------------------------------------------------------------------------
#define TBF 8
__global__ __launch_bounds__(256) void fnn_fused(
    const float* __restrict__ data,
    const float* __restrict__ mu, const float* __restrict__ sigma,
    const float* __restrict__ w3,
    float* __restrict__ out)
{
    __shared__ float d_tile[TBF][NF];
    __shared__ float red[TBF][2][4];

    const int tid = threadIdx.x;
    const int b0  = blockIdx.x * TBF;
    {
        const float4* src = (const float4*)(data + (size_t)b0 * NF);
        ((float4*)(&d_tile[0][0]))[tid] = src[tid];
    }
    __syncthreads();

    const float* mu_r = mu    + (size_t)tid * NF;
    const float* sg_r = sigma + (size_t)tid * NF;
    const float* w_r  = w3    + (size_t)tid * (NF + 1);

    float S[TBF], Q[TBF];
    #pragma unroll
    for (int b = 0; b < TBF; ++b) { S[b] = 0.f; Q[b] = 0.f; }

    #pragma unroll 2
    for (int f = 0; f < NF; f += 4) {
        const float4 m4 = *(const float4*)(mu_r + f);
        const float4 s4 = *(const float4*)(sg_r + f);
        const float w0 = w_r[1 + f + 0], w1 = w_r[1 + f + 1];
        const float w2 = w_r[1 + f + 2], w3v = w_r[1 + f + 3];
        float4 c4;
        c4.x = -0.5f / fmaxf(s4.x * s4.x, 1e-30f);
        c4.y = -0.5f / fmaxf(s4.y * s4.y, 1e-30f);
        c4.z = -0.5f / fmaxf(s4.z * s4.z, 1e-30f);
        c4.w = -0.5f / fmaxf(s4.w * s4.w, 1e-30f);
        #pragma unroll
        for (int b = 0; b < TBF; ++b) {
            const float4 d4 = *(const float4*)(&d_tile[b][f]);
            float t;
            t = d4.x - m4.x; S[b] = fmaf(t * t, c4.x, S[b]); Q[b] = fmaf(d4.x, w0,  Q[b]);
            t = d4.y - m4.y; S[b] = fmaf(t * t, c4.y, S[b]); Q[b] = fmaf(d4.y, w1,  Q[b]);
            t = d4.z - m4.z; S[b] = fmaf(t * t, c4.z, S[b]); Q[b] = fmaf(d4.z, w2,  Q[b]);
            t = d4.w - m4.w; S[b] = fmaf(t * t, c4.w, S[b]); Q[b] = fmaf(d4.w, w3v, Q[b]);
        }
    }

    const float bias = w_r[0];
    #pragma unroll
    for (int b = 0; b < TBF; ++b) {
        float rule = __expf(S[b]) - 28.0f;
        float rc   = rule * (bias + Q[b]);
        #pragma unroll
        for (int off = 32; off > 0; off >>= 1) {
            rule += __shfl_down(rule, off);
            rc   += __shfl_down(rc,   off);
        }
        if ((tid & 63) == 0) {
            red[b][0][tid >> 6] = rule;
            red[b][1][tid >> 6] = rc;
        }
    }
    __syncthreads();
    if (tid < TBF) {
        const float den = red[tid][0][0] + red[tid][0][1] + red[tid][0][2] + red[tid][0][3];
        const float num = red[tid][1][0] + red[tid][1][1] + red[tid][1][2] + red[tid][1][3];
        out[b0 + tid] = 1.0f / (1.0f + __expf(-(num / den)));
    }
}

extern "C" void kernel_launch(void* const* d_in, const int* in_sizes, int n_in,
                              void* d_out, int out_size, void* d_ws, size_t ws_size,
                              hipStream_t stream) {
    const float* data  = (const float*)d_in[0];
    const float* mu    = (const float*)d_in[1];
    const float* sigma = (const float*)d_in[2];
    const float* w3    = (const float*)d_in[3];
    float* out = (float*)d_out;

    const int batch = in_sizes[0] / NF;   // 8192
    // PH + PL + WC (3 x 64K bf16 = 3 x 128 KiB) + Cr + W0 = 395,264 B
    const size_t need = 3u * 65536u * sizeof(unsigned short) + 2u * NR * sizeof(float);

    if (ws_size >= need && (batch % BCOLS) == 0) {
        unsigned short* PH = (unsigned short*)d_ws;
        unsigned short* PL = PH + 65536;
        unsigned short* WC = PL + 65536;
        float* Cr = (float*)(WC + 65536);
        float* W0 = Cr + NR;
        prep_kernel<<<NR, NF, 0, stream>>>(mu, sigma, w3, PH, PL, WC, Cr, W0);
        fnn_mfma<<<batch / BCOLS, 512, 0, stream>>>(data, PH, PL, WC, Cr, W0, out);
    } else {
        fnn_fused<<<batch / TBF, 256, 0, stream>>>(data, mu, sigma, w3, out);
    }
}